// Round 1
// 1278.153 us; speedup vs baseline: 1.1716x; 1.1716x over previous
//
#include <hip/hip_runtime.h>

typedef __attribute__((ext_vector_type(8))) short short8;
typedef __attribute__((ext_vector_type(4))) float floatx4;
typedef __attribute__((ext_vector_type(4))) unsigned short ushort4v;

#define SCALE_F 0.17677669529663687f

__device__ __forceinline__ unsigned short f2bf(float f) {
  union { float f; unsigned u; } v; v.f = f;
  unsigned u = v.u;
  u += 0x7fffu + ((u >> 16) & 1u);   // round-to-nearest-even
  return (unsigned short)(u >> 16);
}

__device__ __forceinline__ void gld_lds16(const void* g, void* l) {
  __builtin_amdgcn_global_load_lds((const __attribute__((address_space(1))) void*)g,
                                   (__attribute__((address_space(3))) void*)l, 16, 0, 0);
}

// fp32 -> bf16 elementwise (n % 8 == 0)
__global__ __launch_bounds__(256)
void cvt_bf16_k(const float* __restrict__ src, unsigned short* __restrict__ dst, long n) {
  long i = ((long)blockIdx.x * 256 + threadIdx.x) * 8;
  if (i >= n) return;
  floatx4 a0 = *(const floatx4*)(src + i);
  floatx4 a1 = *(const floatx4*)(src + i + 4);
  short8 v;
  #pragma unroll
  for (int j = 0; j < 4; ++j) { v[j] = (short)f2bf(a0[j]); v[4 + j] = (short)f2bf(a1[j]); }
  *(short8*)(dst + i) = v;
}

// W[K][N] fp32 -> Wt[N][K] bf16 (K,N % 64 == 0)
__global__ __launch_bounds__(256)
void transcvt_k(const float* __restrict__ W, unsigned short* __restrict__ Wt, int K, int N) {
  __shared__ float t[64][65];
  const int n0 = blockIdx.x * 64, k0 = blockIdx.y * 64;
  const int tx = threadIdx.x & 15, ty = threadIdx.x >> 4;
  #pragma unroll
  for (int r = 0; r < 4; ++r) {
    floatx4 v = *(const floatx4*)&W[(long)(k0 + ty + r * 16) * N + n0 + tx * 4];
    #pragma unroll
    for (int j = 0; j < 4; ++j) t[ty + r * 16][tx * 4 + j] = v[j];
  }
  __syncthreads();
  #pragma unroll
  for (int r = 0; r < 4; ++r) {
    ushort4v o;
    #pragma unroll
    for (int j = 0; j < 4; ++j) o[j] = f2bf(t[tx * 4 + j][ty + r * 16]);
    *(ushort4v*)&Wt[(long)(n0 + ty + r * 16) * K + k0 + tx * 4] = o;
  }
}

// ---------------------------------------------------------------------------
// 256x256 / BK=64 8-phase GEMM (m201-style template in plain HIP).
// C[M,N] = A[M,K] @ Bt[N,K]^T + bias ; A,Bt bf16 row-major, C fp32 or bf16.
// Requirements: M,N % 256 == 0, K % 64 == 0, K/64 >= 2, gridDim.x % 8 == 0.
// 512 threads = 8 waves (2M x 4N), per-wave 128x64 output, 128 KiB LDS dbuf.
// LDS swizzle: granule(16B) ^= (row & 7); applied via inverse-swizzled GLOBAL
// source (linear global_load_lds dest) + same XOR on the ds_read side.
// vmcnt(4) once per K-tile: 2 half-tiles (4 loads) stay in flight across the
// tile boundary; never drained to 0 in the main loop.
// ---------------------------------------------------------------------------
template<bool OUT_F32>
__global__ __launch_bounds__(512, 2)
void gemm256(const unsigned short* __restrict__ A, const unsigned short* __restrict__ Bt,
             const float* __restrict__ bias, void* __restrict__ Cp,
             int M, int N, int K, int ntN) {
  __shared__ __align__(16) unsigned short sm[2][2][256 * 64];  // [buf][A/B][row*64+col]
  (void)M;
  const int tid  = threadIdx.x;
  const int wave = tid >> 6, lane = tid & 63;
  const int quad = lane >> 4, l15 = lane & 15;
  const int wm = wave >> 2, wn = wave & 3;          // 2 x 4 wave grid
  const int xorw = (l15 & 7) << 3;                  // read-side swizzle (ushort units)

  // Bijective XCD-chunked block swizzle (gridDim.x % 8 == 0 by construction).
  const int nwg = gridDim.x;
  const int wg  = (blockIdx.x & 7) * (nwg >> 3) + (blockIdx.x >> 3);
  const int tileN = wg % ntN, tileM = wg / ntN;
  const int NT = K >> 6;

  // Staging invariants: thread covers (row srow within 64-row chunk, granule tid&7),
  // loads global granule sg = (tid&7) ^ (srow&7)  [inverse swizzle].
  const int srow = tid >> 3;
  const int sg   = (tid & 7) ^ (srow & 7);
  const unsigned short* Asrc = A  + (long)(tileM * 256 + srow) * K + sg * 8;
  const unsigned short* Bsrc = Bt + (long)(tileN * 256 + srow) * K + sg * 8;

  // Stage one 128-row half-tile (2 x global_load_lds_dwordx4 per wave).
#define STG(bufi, isB, h, tt) do {                                              \
    const unsigned short* _s = (isB) ? Bsrc : Asrc;                             \
    unsigned short* _d = &sm[bufi][isB][((h) * 128 + wave * 8) * 64];           \
    gld_lds16(_s + (long)((h) * 128) * K + (tt) * 64, _d);                      \
    gld_lds16(_s + (long)((h) * 128 + 64) * K + (tt) * 64, _d + 64 * 64);       \
  } while (0)

#define RD_A(mt, kk) (*(const short8*)&sm[cur][0][(wm * 128 + (mt) * 16 + l15) * 64 + (((kk) * 32 + quad * 8) ^ xorw)])
#define RD_B(nt, kk) (*(const short8*)&sm[cur][1][(wn * 64  + (nt) * 16 + l15) * 64 + (((kk) * 32 + quad * 8) ^ xorw)])

  short8 aF[4][2], bF[4][2];
  floatx4 acc[8][4] = {};

  // ---- Prologue: tile0 fully + first 2 halves of tile1; vmcnt(4) leaves those
  // 4 loads in flight (steady-state invariant at loop entry).
  STG(0, 1, 0, 0);  // Bh0(0)
  STG(0, 0, 0, 0);  // Ah0(0)
  STG(0, 0, 1, 0);  // Ah1(0)
  STG(0, 1, 1, 0);  // Bh1(0)
  if (NT > 1) {
    STG(1, 1, 0, 1);  // Bh0(1)
    STG(1, 0, 0, 1);  // Ah0(1)
    asm volatile("s_waitcnt vmcnt(4)" ::: "memory");
  } else {
    asm volatile("s_waitcnt vmcnt(0)" ::: "memory");
  }
  __builtin_amdgcn_s_barrier();

  for (int t = 0; t < NT; ++t) {
    const int cur = t & 1;
    // ---- Phase 1: read A(mt0-3) + B(nt0-1); issue Ah1(t+1); MFMA Q(lo,lo)
    #pragma unroll
    for (int mt = 0; mt < 4; ++mt)
      #pragma unroll
      for (int kk = 0; kk < 2; ++kk) aF[mt][kk] = RD_A(mt, kk);
    #pragma unroll
    for (int nt = 0; nt < 2; ++nt)
      #pragma unroll
      for (int kk = 0; kk < 2; ++kk) bF[nt][kk] = RD_B(nt, kk);
    if (t + 1 < NT) STG(cur ^ 1, 0, 1, t + 1);
    __builtin_amdgcn_s_barrier();
    asm volatile("s_waitcnt lgkmcnt(0)" ::: "memory");
    __builtin_amdgcn_s_setprio(1);
    #pragma unroll
    for (int mt = 0; mt < 4; ++mt)
      #pragma unroll
      for (int nt = 0; nt < 2; ++nt)
        #pragma unroll
        for (int kk = 0; kk < 2; ++kk)
          acc[mt][nt] = __builtin_amdgcn_mfma_f32_16x16x32_bf16(aF[mt][kk], bF[nt][kk], acc[mt][nt], 0, 0, 0);
    __builtin_amdgcn_s_setprio(0);
    __builtin_amdgcn_s_barrier();

    // ---- Phase 2: read B(nt2-3); issue Bh1(t+1); MFMA Q(lo,hi)
    #pragma unroll
    for (int nt = 2; nt < 4; ++nt)
      #pragma unroll
      for (int kk = 0; kk < 2; ++kk) bF[nt][kk] = RD_B(nt, kk);
    if (t + 1 < NT) STG(cur ^ 1, 1, 1, t + 1);
    __builtin_amdgcn_s_barrier();
    asm volatile("s_waitcnt lgkmcnt(0)" ::: "memory");
    __builtin_amdgcn_s_setprio(1);
    #pragma unroll
    for (int mt = 0; mt < 4; ++mt)
      #pragma unroll
      for (int nt = 2; nt < 4; ++nt)
        #pragma unroll
        for (int kk = 0; kk < 2; ++kk)
          acc[mt][nt] = __builtin_amdgcn_mfma_f32_16x16x32_bf16(aF[mt][kk], bF[nt][kk], acc[mt][nt], 0, 0, 0);
    __builtin_amdgcn_s_setprio(0);
    __builtin_amdgcn_s_barrier();

    // ---- Phase 3: read A(mt4-7) (B regions now dead); issue Bh0(t+2) into cur;
    //      MFMA Q(hi,hi)
    #pragma unroll
    for (int mt = 0; mt < 4; ++mt)
      #pragma unroll
      for (int kk = 0; kk < 2; ++kk) aF[mt][kk] = RD_A(mt + 4, kk);
    if (t + 2 < NT) STG(cur, 1, 0, t + 2);
    __builtin_amdgcn_s_barrier();
    asm volatile("s_waitcnt lgkmcnt(0)" ::: "memory");
    __builtin_amdgcn_s_setprio(1);
    #pragma unroll
    for (int mt = 0; mt < 4; ++mt)
      #pragma unroll
      for (int nt = 2; nt < 4; ++nt)
        #pragma unroll
        for (int kk = 0; kk < 2; ++kk)
          acc[mt + 4][nt] = __builtin_amdgcn_mfma_f32_16x16x32_bf16(aF[mt][kk], bF[nt][kk], acc[mt + 4][nt], 0, 0, 0);
    __builtin_amdgcn_s_setprio(0);
    __builtin_amdgcn_s_barrier();

    // ---- Phase 4: (A regions now dead) issue Ah0(t+2) into cur; MFMA Q(hi,lo);
    //      counted vmcnt confirms all of tile t+1, leaves t+2's 2 halves in flight.
    if (t + 2 < NT) STG(cur, 0, 0, t + 2);
    __builtin_amdgcn_s_setprio(1);
    #pragma unroll
    for (int mt = 0; mt < 4; ++mt)
      #pragma unroll
      for (int nt = 0; nt < 2; ++nt)
        #pragma unroll
        for (int kk = 0; kk < 2; ++kk)
          acc[mt + 4][nt] = __builtin_amdgcn_mfma_f32_16x16x32_bf16(aF[mt][kk], bF[nt][kk], acc[mt + 4][nt], 0, 0, 0);
    __builtin_amdgcn_s_setprio(0);
    if (t + 2 < NT)      { asm volatile("s_waitcnt vmcnt(4)" ::: "memory"); }
    else if (t + 1 < NT) { asm volatile("s_waitcnt vmcnt(0)" ::: "memory"); }
    __builtin_amdgcn_s_barrier();
  }
#undef STG
#undef RD_A
#undef RD_B

  // ---- Epilogue: bias + store
  float bv[4];
  #pragma unroll
  for (int nt = 0; nt < 4; ++nt) bv[nt] = bias[tileN * 256 + wn * 64 + nt * 16 + l15];
  #pragma unroll
  for (int mt = 0; mt < 8; ++mt)
    #pragma unroll
    for (int nt = 0; nt < 4; ++nt)
      #pragma unroll
      for (int r = 0; r < 4; ++r) {
        long rg = (long)tileM * 256 + wm * 128 + mt * 16 + quad * 4 + r;
        long cg = (long)tileN * 256 + wn * 64 + nt * 16 + l15;
        float val = acc[mt][nt][r] + bv[nt];
        if (OUT_F32) ((float*)Cp)[rg * (long)N + cg] = val;
        else         ((unsigned short*)Cp)[rg * (long)N + cg] = f2bf(val);
      }
}

// One wave per (window-batch b, head h). N=49 padded to 64, hd=32.
__global__ __launch_bounds__(256)
void attn_k(const unsigned short* __restrict__ qkv, const float* __restrict__ mask,
            const float* __restrict__ bias_table, unsigned short* __restrict__ attn_out) {
  __shared__ __align__(16) unsigned short P[4][64][72];
  const int wave = threadIdx.x >> 6, lane = threadIdx.x & 63;
  const int quad = lane >> 4, l15 = lane & 15;
  const int flat = blockIdx.x * 4 + wave;
  const int b = flat / 24, h = flat % 24;

  const unsigned short* qbase = qkv + (long)b * 49 * 2304 + h * 32;
  const unsigned short* kbase = qbase + 768;
  const unsigned short* vbase = qbase + 1536;

  short8 qF[4], kF[4];
  #pragma unroll
  for (int mt = 0; mt < 4; ++mt) {
    int m = mt * 16 + l15; int me = m < 49 ? m : 48;
    qF[mt] = *(const short8*)(qbase + (long)me * 2304 + quad * 8);
  }
  #pragma unroll
  for (int nt = 0; nt < 4; ++nt) {
    int n = nt * 16 + l15; int ne = n < 49 ? n : 48;
    kF[nt] = *(const short8*)(kbase + (long)ne * 2304 + quad * 8);
  }

  floatx4 sc[4][4] = {};
  #pragma unroll
  for (int mt = 0; mt < 4; ++mt)
    #pragma unroll
    for (int nt = 0; nt < 4; ++nt)
      sc[mt][nt] = __builtin_amdgcn_mfma_f32_16x16x32_bf16(qF[mt], kF[nt], sc[mt][nt], 0, 0, 0);

  const int w = b & 63;
  const float* mrow = mask + (long)w * 49 * 49;
  #pragma unroll
  for (int mt = 0; mt < 4; ++mt)
    #pragma unroll
    for (int r = 0; r < 4; ++r) {
      int i = mt * 16 + quad * 4 + r;
      bool iv = i < 49;
      int ri = i / 7, ci = i % 7;
      float vals[4];
      float vmax = -1e30f;
      #pragma unroll
      for (int nt = 0; nt < 4; ++nt) {
        int j = nt * 16 + l15;
        float v = -1e30f;
        if (iv && j < 49) {
          int rj = j / 7, cj = j % 7;
          int idx = (ri - rj + 6) * 13 + (ci - cj + 6);
          v = sc[mt][nt][r] * SCALE_F + bias_table[idx * 24 + h] + mrow[i * 49 + j];
        }
        vals[nt] = v;
        vmax = fmaxf(vmax, v);
      }
      #pragma unroll
      for (int d = 1; d < 16; d <<= 1) vmax = fmaxf(vmax, __shfl_xor(vmax, d));
      float sum = 0.f;
      #pragma unroll
      for (int nt = 0; nt < 4; ++nt) { float e = __expf(vals[nt] - vmax); vals[nt] = e; sum += e; }
      #pragma unroll
      for (int d = 1; d < 16; d <<= 1) sum += __shfl_xor(sum, d);
      float inv = 1.0f / sum;
      #pragma unroll
      for (int nt = 0; nt < 4; ++nt)
        P[wave][i][nt * 16 + l15] = f2bf(vals[nt] * inv);
    }
  __syncthreads();

  floatx4 o[4][2] = {};
  #pragma unroll
  for (int kt = 0; kt < 2; ++kt) {
    short8 pF[4];
    #pragma unroll
    for (int mt = 0; mt < 4; ++mt)
      pF[mt] = *(const short8*)&P[wave][mt * 16 + l15][kt * 32 + quad * 8];
    short8 vF[2];
    #pragma unroll
    for (int nt = 0; nt < 2; ++nt) {
      short8 t;
      #pragma unroll
      for (int jj = 0; jj < 8; ++jj) {
        int j = kt * 32 + quad * 8 + jj; int je = j < 49 ? j : 48;
        t[jj] = (short)vbase[(long)je * 2304 + nt * 16 + l15];
      }
      vF[nt] = t;
    }
    #pragma unroll
    for (int mt = 0; mt < 4; ++mt)
      #pragma unroll
      for (int nt = 0; nt < 2; ++nt)
        o[mt][nt] = __builtin_amdgcn_mfma_f32_16x16x32_bf16(pF[mt], vF[nt], o[mt][nt], 0, 0, 0);
  }

  unsigned short* obase = attn_out + (long)b * 49 * 768 + h * 32;
  #pragma unroll
  for (int mt = 0; mt < 4; ++mt)
    #pragma unroll
    for (int nt = 0; nt < 2; ++nt)
      #pragma unroll
      for (int r = 0; r < 4; ++r) {
        int i = mt * 16 + quad * 4 + r;
        if (i < 49) obase[(long)i * 768 + nt * 16 + l15] = f2bf(o[mt][nt][r]);
      }
}

extern "C" void kernel_launch(void* const* d_in, const int* in_sizes, int n_in,
                              void* d_out, int out_size, void* d_ws, size_t ws_size,
                              hipStream_t stream) {
  const float* x          = (const float*)d_in[0];
  const float* mask       = (const float*)d_in[1];
  const float* qkv_w      = (const float*)d_in[2];
  const float* qkv_b      = (const float*)d_in[3];
  const float* proj_w     = (const float*)d_in[4];
  const float* proj_b     = (const float*)d_in[5];
  const float* bias_table = (const float*)d_in[6];

  // Scratch layout:
  //  d_out (308 MB fp32 out): xb bf16 (154.1 MB) + qkv_wt bf16 (3.5 MB) — both dead before K3 writes d_out.
  //  d_ws: qkv bf16 (462.4 MB) + attn bf16 (154.1 MB). proj_wt reuses qkv region after attn_k consumes it.
  unsigned short* xb      = (unsigned short*)d_out;
  unsigned short* qkv_wt  = (unsigned short*)d_out + (size_t)100352 * 768;
  unsigned short* qkv     = (unsigned short*)d_ws;
  unsigned short* attn    = qkv + (size_t)100352 * 2304;
  unsigned short* proj_wt = qkv;  // written after attn_k; qkv dead by then
  float* out = (float*)d_out;

  const long nx = (long)100352 * 768;
  cvt_bf16_k<<<(nx / 8 + 255) / 256, 256, 0, stream>>>(x, xb, nx);
  transcvt_k<<<dim3(36, 12), 256, 0, stream>>>(qkv_w, qkv_wt, 768, 2304);
  // K1: QKV projection (bf16 x bf16 -> bf16). grid = 9*392 = 3528 (% 8 == 0)
  gemm256<false><<<dim3(3528), 512, 0, stream>>>(xb, qkv_wt, qkv_b, qkv, 100352, 2304, 768, 9);
  // K2: windowed attention
  attn_k<<<12288, 256, 0, stream>>>(qkv, mask, bias_table, attn);
  // proj weights transpose into dead qkv region
  transcvt_k<<<dim3(12, 12), 256, 0, stream>>>(proj_w, proj_wt, 768, 768);
  // K3: output projection (bf16 x bf16 -> fp32). grid = 3*392 = 1176 (% 8 == 0)
  gemm256<true><<<dim3(1176), 512, 0, stream>>>(attn, proj_wt, proj_b, out, 100352, 768, 768, 3);
}